// Round 11
// baseline (160.100 us; speedup 1.0000x reference)
//
#include <hip/hip_runtime.h>
#include <hip/hip_bf16.h>

#define HW    4096
#define CIN   256
#define NB    8
#define T_FR  8
#define CTX_ELEMS (NB * 256 * 512)      // 1,048,576 = 2^20

typedef __attribute__((ext_vector_type(8))) short short8;
typedef __attribute__((ext_vector_type(4))) float f32x4;

__device__ __forceinline__ unsigned short f2bf(float f) {
  __hip_bfloat16 h = __float2bfloat16(f);
  union { __hip_bfloat16 h; unsigned short u; } v; v.h = h;
  return v.u;
}
__device__ __forceinline__ float bf2f(unsigned short u) {
  union { unsigned int u; float f; } v; v.u = ((unsigned int)u) << 16;
  return v.f;
}

// ---------------------------------------------------------------------------
// k_main: merged att + feat, 256-p tile (64 p per wave, acc[4][4]).
//   blocks [0,1024):    att: (pb = bid&15, s = bid>>4)
//   blocks [1024,1536): feat: (fb=bid-1024: pb = fb&15, g=fb>>4, ftile=g&3, b=g>>2)
// A = x^T per-lane direct global gather (f32->bf16), B = 64xCIN weight slice
// staged bf16 in LDS.  33.8 KB LDS.   (unchanged from round 9)
// ---------------------------------------------------------------------------
#define LROW 264
__global__ __launch_bounds__(256) void k_main(
    const float* __restrict__ x, const float* __restrict__ Wa,
    const float* __restrict__ Wf, const float* __restrict__ batt,
    const float* __restrict__ bfeat, unsigned short* __restrict__ attbf,
    unsigned short* __restrict__ featbf, float* __restrict__ rsum_part) {
  const int bid = blockIdx.x;
  __shared__ unsigned short Wsh[64 * LROW];    // 33.8 KB
  __shared__ float wsum[4][64];
  const int tid = threadIdx.x, lane = tid & 63, wave = tid >> 6;

  const bool is_att = bid < 1024;
  int pb, s, ftile, b;
  const float* Wsrc;
  if (is_att) {
    pb = bid & 15; s = bid >> 4; ftile = 0; b = 0;
    Wsrc = Wa;
  } else {
    const int fb = bid - 1024;
    pb = fb & 15;
    const int g = fb >> 4;
    ftile = g & 3; b = g >> 2; s = b * T_FR;   // frame 0 of clip b
    Wsrc = Wf + (size_t)(ftile * 64) * CIN;
  }

  // stage 64 rows x 256 cols of Wsrc -> bf16 LDS
  {
    const int row = tid >> 2, seg = tid & 3;
    const float* src = Wsrc + (size_t)row * CIN + seg * 64;
    unsigned short* dst = &Wsh[row * LROW + seg * 64];
#pragma unroll
    for (int i = 0; i < 8; ++i) {
      float4 va = *(const float4*)(src + i * 8);
      float4 vb = *(const float4*)(src + i * 8 + 4);
      short8 w;
      w[0] = (short)f2bf(va.x); w[1] = (short)f2bf(va.y);
      w[2] = (short)f2bf(va.z); w[3] = (short)f2bf(va.w);
      w[4] = (short)f2bf(vb.x); w[5] = (short)f2bf(vb.y);
      w[6] = (short)f2bf(vb.z); w[7] = (short)f2bf(vb.w);
      *(short8*)(dst + i * 8) = w;
    }
  }
  __syncthreads();

  const int r = lane & 15, kg = lane >> 4;
  const int pw = pb * 256 + wave * 64;
  const float* xs = x + (size_t)s * CIN * HW;
  f32x4 acc[4][4] = {};
  for (int ks = 0; ks < 8; ++ks) {
    short8 afr[4];
#pragma unroll
    for (int mi = 0; mi < 4; ++mi) {
      const float* col = xs + (size_t)(ks * 32 + kg * 8) * HW + pw + mi * 16 + r;
#pragma unroll
      for (int j = 0; j < 8; ++j) afr[mi][j] = (short)f2bf(col[(size_t)j * HW]);
    }
    short8 bfr[4];
#pragma unroll
    for (int nj = 0; nj < 4; ++nj)
      bfr[nj] = *(const short8*)&Wsh[(nj * 16 + r) * LROW + ks * 32 + kg * 8];
#pragma unroll
    for (int mi = 0; mi < 4; ++mi)
#pragma unroll
      for (int nj = 0; nj < 4; ++nj)
        acc[mi][nj] = __builtin_amdgcn_mfma_f32_16x16x32_bf16(afr[mi], bfr[nj], acc[mi][nj], 0, 0, 0);
  }

  if (is_att) {
    const int bb = s >> 3, t = s & 7;
    float rowpart[4];
#pragma unroll
    for (int nj = 0; nj < 4; ++nj) {
      const int a = nj * 16 + r;
      const float bias = batt[a];
      float sp = 0.f;
#pragma unroll
      for (int mi = 0; mi < 4; ++mi) {
        float e0 = __expf(acc[mi][nj][0] + bias);
        float e1 = __expf(acc[mi][nj][1] + bias);
        float e2 = __expf(acc[mi][nj][2] + bias);
        float e3 = __expf(acc[mi][nj][3] + bias);
        sp += e0 + e1 + e2 + e3;
        ushort4 u;
        u.x = f2bf(e0); u.y = f2bf(e1); u.z = f2bf(e2); u.w = f2bf(e3);
        *(ushort4*)&attbf[(size_t)(bb * 512 + t * 64 + a) * HW + pw + mi * 16 + kg * 4] = u;
      }
      sp += __shfl_xor(sp, 16);
      sp += __shfl_xor(sp, 32);
      rowpart[nj] = sp;
    }
    if (lane < 16) {
#pragma unroll
      for (int nj = 0; nj < 4; ++nj) wsum[wave][nj * 16 + r] = rowpart[nj];
    }
    __syncthreads();
    if (tid < 64) {
      float tot = wsum[0][tid] + wsum[1][tid] + wsum[2][tid] + wsum[3][tid];
      rsum_part[(size_t)pb * 4096 + bb * 512 + t * 64 + tid] = tot;
    }
  } else {
#pragma unroll
    for (int nj = 0; nj < 4; ++nj) {
      const int f = ftile * 64 + nj * 16 + r;
      const float bias = bfeat[f];
#pragma unroll
      for (int mi = 0; mi < 4; ++mi) {
        ushort4 u;
        u.x = f2bf(acc[mi][nj][0] + bias);
        u.y = f2bf(acc[mi][nj][1] + bias);
        u.z = f2bf(acc[mi][nj][2] + bias);
        u.w = f2bf(acc[mi][nj][3] + bias);
        *(ushort4*)&featbf[(size_t)(b * 256 + f) * HW + pw + mi * 16 + kg * 4] = u;
      }
    }
  }
}

// ---------------------------------------------------------------------------
// k_ctx: 5120 blocks, LDS-FREE (16 B shared only -> occupancy VGPR-bound,
// no barriers in the GEMM path, normalize blocks co-schedule freely).
//   blocks [0,1024): split-K(8) partial GEMM, A AND B per-lane direct-global
//     (identical 16-rows x 64B-segment coalescing pattern for both).
//     a0=(bid&7)*64, ft=(bid>>3)&1, z=bid>>4, b=z>>3, kc=z&7.
//     blocks bid<256 with (bid&15)==0 also reduce rsum (z<16: guard FIXED).
//   blocks [1024,5120): attn-normalize, one row each (local row-sum from the
//     bf16 row -> no rsum dependency, no race).
// ---------------------------------------------------------------------------
__global__ __launch_bounds__(256) void k_ctx(
    const unsigned short* __restrict__ featbf,
    const unsigned short* __restrict__ attbf,
    const float* __restrict__ rsum_part,
    float* __restrict__ rsum,
    float* __restrict__ partial,
    float* __restrict__ attn) {
  const int bid = blockIdx.x;
  const int tid = threadIdx.x, lane = tid & 63, wave = tid >> 6;
  __shared__ float redsh[4];

  if (bid >= 1024) {
    // ---- attn-normalize block: one row ----
    const int row = bid - 1024;
    const unsigned short* src = attbf + (size_t)row * HW;
    float* dst = attn + (size_t)row * HW;
    short8 v0 = *(const short8*)(src + tid * 16);
    short8 v1 = *(const short8*)(src + tid * 16 + 8);
    float f[16];
#pragma unroll
    for (int k = 0; k < 8; ++k) f[k] = bf2f((unsigned short)v0[k]);
#pragma unroll
    for (int k = 0; k < 8; ++k) f[8 + k] = bf2f((unsigned short)v1[k]);
    float s = 0.f;
#pragma unroll
    for (int k = 0; k < 16; ++k) s += f[k];
#pragma unroll
    for (int off = 32; off > 0; off >>= 1) s += __shfl_xor(s, off);
    if (lane == 0) redsh[wave] = s;
    __syncthreads();
    const float inv = 1.0f / (redsh[0] + redsh[1] + redsh[2] + redsh[3]);
#pragma unroll
    for (int q = 0; q < 4; ++q) {
      float4 o;
      o.x = f[q * 4 + 0] * inv; o.y = f[q * 4 + 1] * inv;
      o.z = f[q * 4 + 2] * inv; o.w = f[q * 4 + 3] * inv;
      *(float4*)(dst + tid * 16 + q * 4) = o;
    }
    return;
  }

  // ---- GEMM block ----
  const int a0 = (bid & 7) * 64;
  const int ft = (bid >> 3) & 1;
  const int z  = bid >> 4;
  const int b  = z >> 3;
  const int kc = z & 7;

  // fused rsum: 16 blocks (z<16) x 256 threads cover all 4096 rows
  if (bid < 256 && (bid & 15) == 0) {
    const int row = z * 256 + tid;
    float s = 0.f;
#pragma unroll
    for (int j = 0; j < 16; ++j) s += rsum_part[(size_t)j * 4096 + row];
    rsum[row] = s;
  }

  const int r = lane & 15, kg = lane >> 4;
  const int fbase = ft * 128 + wave * 32;
  const unsigned short* Arow = featbf + (size_t)(b * 256 + fbase + r) * HW + kc * 512 + kg * 8;
  const unsigned short* Brow = attbf + (size_t)(b * 512 + a0 + r) * HW + kc * 512 + kg * 8;
  f32x4 acc[2][4] = {};
#pragma unroll
  for (int ks = 0; ks < 16; ++ks) {
    short8 afr[2];
    afr[0] = *(const short8*)(Arow + ks * 32);
    afr[1] = *(const short8*)(Arow + ks * 32 + (size_t)16 * HW);
    short8 bfr[4];
#pragma unroll
    for (int nj = 0; nj < 4; ++nj)
      bfr[nj] = *(const short8*)(Brow + ks * 32 + (size_t)(nj * 16) * HW);
#pragma unroll
    for (int mi = 0; mi < 2; ++mi)
#pragma unroll
      for (int nj = 0; nj < 4; ++nj)
        acc[mi][nj] = __builtin_amdgcn_mfma_f32_16x16x32_bf16(afr[mi], bfr[nj], acc[mi][nj], 0, 0, 0);
  }
  const size_t base = ((size_t)kc << 20) + (size_t)b * (256 * 512);
#pragma unroll
  for (int mi = 0; mi < 2; ++mi)
#pragma unroll
    for (int nj = 0; nj < 4; ++nj)
#pragma unroll
      for (int reg = 0; reg < 4; ++reg) {
        const int f = fbase + mi * 16 + kg * 4 + reg;
        const int a = a0 + nj * 16 + r;
        partial[base + (size_t)f * 512 + a] = acc[mi][nj][reg];
      }
}

// ---------------------------------------------------------------------------
// k_final: ctxred only, float4-vectorized.  1024 blocks.
// ---------------------------------------------------------------------------
__global__ __launch_bounds__(256) void k_final(
    const float* __restrict__ partial, const float* __restrict__ rsum,
    float* __restrict__ ctx) {
  const int i4 = (blockIdx.x * 256 + threadIdx.x) * 4;
  const int a = i4 & 511, b = i4 >> 17;
  float4 s = *(const float4*)&partial[i4];
#pragma unroll
  for (int kc = 1; kc < 8; ++kc) {
    float4 p = *(const float4*)&partial[((size_t)kc << 20) + i4];
    s.x += p.x; s.y += p.y; s.z += p.z; s.w += p.w;
  }
  const float4 rs = *(const float4*)&rsum[b * 512 + a];
  s.x /= rs.x; s.y /= rs.y; s.z /= rs.z; s.w /= rs.w;
  *(float4*)&ctx[i4] = s;
}

// ---------------------------------------------------------------------------
extern "C" void kernel_launch(void* const* d_in, const int* in_sizes, int n_in,
                              void* d_out, int out_size, void* d_ws, size_t ws_size,
                              hipStream_t stream) {
  const float* x     = (const float*)d_in[0];
  const float* Wf    = (const float*)d_in[1];
  const float* bfeat = (const float*)d_in[2];
  const float* Wa    = (const float*)d_in[3];
  const float* ba    = (const float*)d_in[4];
  float* ctx  = (float*)d_out;
  float* attn = ctx + CTX_ELEMS;

  unsigned short* featbf = (unsigned short*)d_ws;                 // 16.8 MB
  unsigned short* attbf  = featbf + (size_t)NB * 256 * HW;        // 33.6 MB
  float* rsum_part = (float*)(attbf + (size_t)4096 * HW);         // 256 KB (16 pblocks)
  float* rsum = rsum_part + 16 * 4096;                            // 16 KB
  float* partial = rsum + 4096;                                   // 33.6 MB (8 x 4 MB)

  k_main<<<1536, 256, 0, stream>>>(x, Wa, Wf, ba, bfeat, attbf, featbf, rsum_part);
  k_ctx<<<5120, 256, 0, stream>>>(featbf, attbf, rsum_part, rsum, partial, attn);
  k_final<<<1024, 256, 0, stream>>>(partial, rsum, ctx);
}

// Round 12
// 149.192 us; speedup vs baseline: 1.0731x; 1.0731x over previous
//
#include <hip/hip_runtime.h>
#include <hip/hip_bf16.h>

#define HW    4096
#define CIN   256
#define NB    8
#define T_FR  8
#define CTX_ELEMS (NB * 256 * 512)      // 1,048,576 = 2^20

typedef __attribute__((ext_vector_type(8))) short short8;
typedef __attribute__((ext_vector_type(4))) float f32x4;

__device__ __forceinline__ unsigned short f2bf(float f) {
  __hip_bfloat16 h = __float2bfloat16(f);
  union { __hip_bfloat16 h; unsigned short u; } v; v.h = h;
  return v.u;
}
__device__ __forceinline__ float bf2f(unsigned short u) {
  union { unsigned int u; float f; } v; v.u = ((unsigned int)u) << 16;
  return v.f;
}

// ---------------------------------------------------------------------------
// k_main: merged att + feat, 256-p tile (64 p per wave, acc[4][4]).
//   blocks [0,1024):    att: (pb = bid&15, s = bid>>4)
//   blocks [1024,1536): feat: (fb=bid-1024: pb = fb&15, g=fb>>4, ftile=g&3, b=g>>2)
// A = x^T per-lane direct global gather (f32->bf16), B = 64xCIN weight slice
// staged bf16 in LDS.  33.8 KB LDS.   (round-9 proven version, verbatim)
// ---------------------------------------------------------------------------
#define LROW 264
__global__ __launch_bounds__(256) void k_main(
    const float* __restrict__ x, const float* __restrict__ Wa,
    const float* __restrict__ Wf, const float* __restrict__ batt,
    const float* __restrict__ bfeat, unsigned short* __restrict__ attbf,
    unsigned short* __restrict__ featbf, float* __restrict__ rsum_part) {
  const int bid = blockIdx.x;
  __shared__ unsigned short Wsh[64 * LROW];    // 33.8 KB
  __shared__ float wsum[4][64];
  const int tid = threadIdx.x, lane = tid & 63, wave = tid >> 6;

  const bool is_att = bid < 1024;
  int pb, s, ftile, b;
  const float* Wsrc;
  if (is_att) {
    pb = bid & 15; s = bid >> 4; ftile = 0; b = 0;
    Wsrc = Wa;
  } else {
    const int fb = bid - 1024;
    pb = fb & 15;
    const int g = fb >> 4;
    ftile = g & 3; b = g >> 2; s = b * T_FR;   // frame 0 of clip b
    Wsrc = Wf + (size_t)(ftile * 64) * CIN;
  }

  // stage 64 rows x 256 cols of Wsrc -> bf16 LDS
  {
    const int row = tid >> 2, seg = tid & 3;
    const float* src = Wsrc + (size_t)row * CIN + seg * 64;
    unsigned short* dst = &Wsh[row * LROW + seg * 64];
#pragma unroll
    for (int i = 0; i < 8; ++i) {
      float4 va = *(const float4*)(src + i * 8);
      float4 vb = *(const float4*)(src + i * 8 + 4);
      short8 w;
      w[0] = (short)f2bf(va.x); w[1] = (short)f2bf(va.y);
      w[2] = (short)f2bf(va.z); w[3] = (short)f2bf(va.w);
      w[4] = (short)f2bf(vb.x); w[5] = (short)f2bf(vb.y);
      w[6] = (short)f2bf(vb.z); w[7] = (short)f2bf(vb.w);
      *(short8*)(dst + i * 8) = w;
    }
  }
  __syncthreads();

  const int r = lane & 15, kg = lane >> 4;
  const int pw = pb * 256 + wave * 64;
  const float* xs = x + (size_t)s * CIN * HW;
  f32x4 acc[4][4] = {};
  for (int ks = 0; ks < 8; ++ks) {
    short8 afr[4];
#pragma unroll
    for (int mi = 0; mi < 4; ++mi) {
      const float* col = xs + (size_t)(ks * 32 + kg * 8) * HW + pw + mi * 16 + r;
#pragma unroll
      for (int j = 0; j < 8; ++j) afr[mi][j] = (short)f2bf(col[(size_t)j * HW]);
    }
    short8 bfr[4];
#pragma unroll
    for (int nj = 0; nj < 4; ++nj)
      bfr[nj] = *(const short8*)&Wsh[(nj * 16 + r) * LROW + ks * 32 + kg * 8];
#pragma unroll
    for (int mi = 0; mi < 4; ++mi)
#pragma unroll
      for (int nj = 0; nj < 4; ++nj)
        acc[mi][nj] = __builtin_amdgcn_mfma_f32_16x16x32_bf16(afr[mi], bfr[nj], acc[mi][nj], 0, 0, 0);
  }

  if (is_att) {
    const int bb = s >> 3, t = s & 7;
    float rowpart[4];
#pragma unroll
    for (int nj = 0; nj < 4; ++nj) {
      const int a = nj * 16 + r;
      const float bias = batt[a];
      float sp = 0.f;
#pragma unroll
      for (int mi = 0; mi < 4; ++mi) {
        float e0 = __expf(acc[mi][nj][0] + bias);
        float e1 = __expf(acc[mi][nj][1] + bias);
        float e2 = __expf(acc[mi][nj][2] + bias);
        float e3 = __expf(acc[mi][nj][3] + bias);
        sp += e0 + e1 + e2 + e3;
        ushort4 u;
        u.x = f2bf(e0); u.y = f2bf(e1); u.z = f2bf(e2); u.w = f2bf(e3);
        *(ushort4*)&attbf[(size_t)(bb * 512 + t * 64 + a) * HW + pw + mi * 16 + kg * 4] = u;
      }
      sp += __shfl_xor(sp, 16);
      sp += __shfl_xor(sp, 32);
      rowpart[nj] = sp;
    }
    if (lane < 16) {
#pragma unroll
      for (int nj = 0; nj < 4; ++nj) wsum[wave][nj * 16 + r] = rowpart[nj];
    }
    __syncthreads();
    if (tid < 64) {
      float tot = wsum[0][tid] + wsum[1][tid] + wsum[2][tid] + wsum[3][tid];
      rsum_part[(size_t)pb * 4096 + bb * 512 + t * 64 + tid] = tot;
    }
  } else {
#pragma unroll
    for (int nj = 0; nj < 4; ++nj) {
      const int f = ftile * 64 + nj * 16 + r;
      const float bias = bfeat[f];
#pragma unroll
      for (int mi = 0; mi < 4; ++mi) {
        ushort4 u;
        u.x = f2bf(acc[mi][nj][0] + bias);
        u.y = f2bf(acc[mi][nj][1] + bias);
        u.z = f2bf(acc[mi][nj][2] + bias);
        u.w = f2bf(acc[mi][nj][3] + bias);
        *(ushort4*)&featbf[(size_t)(b * 256 + f) * HW + pw + mi * 16 + kg * 4] = u;
      }
    }
  }
}

// ---------------------------------------------------------------------------
// k_ctx: split-K(8) partial GEMM (round-9 inner loop verbatim) + fused rsum.
// XCD-aware flattened grid (T1): bid = atile*128 + ft*64 + z, so all 16
// blocks sharing a (b,kc) panel group are congruent mod 8 -> same XCD L2:
// featbf 256-row panel + attbf 512-row slab fetched once per XCD, not 8x.
//   atile = bid>>7, ft = (bid>>6)&1, z = bid&63 (b = z>>3, kc = z&7).
//   blocks bid<16 (atile=0, ft=0, z<16) also reduce rsum_part -> rsum
//   (rsum consumed only by k_final).
// Block: 128f x 64a, K = 512.  1024 blocks, 33.8 KB LDS.
// ---------------------------------------------------------------------------
__global__ __launch_bounds__(256) void k_ctx(
    const unsigned short* __restrict__ featbf,
    const unsigned short* __restrict__ attbf,
    const float* __restrict__ rsum_part,
    float* __restrict__ rsum,
    float* __restrict__ partial) {
  const int bid = blockIdx.x;
  const int a0 = (bid >> 7) * 64;
  const int ft = (bid >> 6) & 1;
  const int z  = bid & 63;
  const int b  = z >> 3;
  const int kc = z & 7;
  const int tid = threadIdx.x, lane = tid & 63, wave = tid >> 6;

  // fused rsum: 16 blocks x 256 threads cover all 4096 rows
  if (bid < 16) {
    const int row = z * 256 + tid;
    float s = 0.f;
#pragma unroll
    for (int j = 0; j < 16; ++j) s += rsum_part[(size_t)j * 4096 + row];
    rsum[row] = s;
  }

  __shared__ unsigned short Bsh[64 * LROW];    // 33.8 KB
  const int r = lane & 15, kg = lane >> 4;
  const int fbase = ft * 128 + wave * 32;
  const unsigned short* Arow = featbf + (size_t)(b * 256 + fbase + r) * HW + kc * 512 + kg * 8;
  const unsigned short* Bsrc = attbf + (size_t)(b * 512 + a0 + (tid >> 2)) * HW + kc * 512 + (tid & 3) * 64;
  unsigned short* Bdst = &Bsh[(tid >> 2) * LROW + (tid & 3) * 64];
  f32x4 acc[2][4] = {};
  for (int ch = 0; ch < 2; ++ch) {
    __syncthreads();
#pragma unroll
    for (int i = 0; i < 8; ++i)
      *(short8*)(Bdst + i * 8) = *(const short8*)(Bsrc + ch * 256 + i * 8);
    __syncthreads();
#pragma unroll
    for (int ks = 0; ks < 8; ++ks) {
      short8 afr[2];
      afr[0] = *(const short8*)(Arow + ch * 256 + ks * 32);
      afr[1] = *(const short8*)(Arow + ch * 256 + ks * 32 + (size_t)16 * HW);
      short8 bfr[4];
#pragma unroll
      for (int nj = 0; nj < 4; ++nj)
        bfr[nj] = *(const short8*)&Bsh[(nj * 16 + r) * LROW + ks * 32 + kg * 8];
#pragma unroll
      for (int mi = 0; mi < 2; ++mi)
#pragma unroll
        for (int nj = 0; nj < 4; ++nj)
          acc[mi][nj] = __builtin_amdgcn_mfma_f32_16x16x32_bf16(afr[mi], bfr[nj], acc[mi][nj], 0, 0, 0);
    }
  }
  const size_t base = ((size_t)kc << 20) + (size_t)b * (256 * 512);
#pragma unroll
  for (int mi = 0; mi < 2; ++mi)
#pragma unroll
    for (int nj = 0; nj < 4; ++nj)
#pragma unroll
      for (int reg = 0; reg < 4; ++reg) {
        const int f = fbase + mi * 16 + kg * 4 + reg;
        const int a = a0 + nj * 16 + r;
        partial[base + (size_t)f * 512 + a] = acc[mi][nj][reg];
      }
}

// ---------------------------------------------------------------------------
// k_final: merged epilogue (round-9 verbatim).
//   blocks [0,1024):    ctxred, float4-vectorized.
//   blocks [1024,5120): attn[row,:] = e_bf16[row,:] / rsum[row]
// ---------------------------------------------------------------------------
__global__ __launch_bounds__(256) void k_final(
    const float* __restrict__ partial, const float* __restrict__ rsum,
    const unsigned short* __restrict__ attbf,
    float* __restrict__ ctx, float* __restrict__ attn) {
  if (blockIdx.x < 1024) {
    const int i4 = (blockIdx.x * 256 + threadIdx.x) * 4;
    const int a = i4 & 511, b = i4 >> 17;
    float4 s = *(const float4*)&partial[i4];
#pragma unroll
    for (int kc = 1; kc < 8; ++kc) {
      float4 p = *(const float4*)&partial[((size_t)kc << 20) + i4];
      s.x += p.x; s.y += p.y; s.z += p.z; s.w += p.w;
    }
    const float4 rs = *(const float4*)&rsum[b * 512 + a];
    s.x /= rs.x; s.y /= rs.y; s.z /= rs.z; s.w /= rs.w;
    *(float4*)&ctx[i4] = s;
  } else {
    const int row = blockIdx.x - 1024;
    const float inv = 1.0f / rsum[row];
    const unsigned short* src = attbf + (size_t)row * HW;
    float* dst = attn + (size_t)row * HW;
    const int tid = threadIdx.x;
#pragma unroll
    for (int i = 0; i < 2; ++i) {
      short8 v = *(const short8*)(src + tid * 8 + i * 2048);
      float4 o0, o1;
      o0.x = bf2f((unsigned short)v[0]) * inv;
      o0.y = bf2f((unsigned short)v[1]) * inv;
      o0.z = bf2f((unsigned short)v[2]) * inv;
      o0.w = bf2f((unsigned short)v[3]) * inv;
      o1.x = bf2f((unsigned short)v[4]) * inv;
      o1.y = bf2f((unsigned short)v[5]) * inv;
      o1.z = bf2f((unsigned short)v[6]) * inv;
      o1.w = bf2f((unsigned short)v[7]) * inv;
      *(float4*)(dst + tid * 8 + i * 2048) = o0;
      *(float4*)(dst + tid * 8 + i * 2048 + 4) = o1;
    }
  }
}

// ---------------------------------------------------------------------------
extern "C" void kernel_launch(void* const* d_in, const int* in_sizes, int n_in,
                              void* d_out, int out_size, void* d_ws, size_t ws_size,
                              hipStream_t stream) {
  const float* x     = (const float*)d_in[0];
  const float* Wf    = (const float*)d_in[1];
  const float* bfeat = (const float*)d_in[2];
  const float* Wa    = (const float*)d_in[3];
  const float* ba    = (const float*)d_in[4];
  float* ctx  = (float*)d_out;
  float* attn = ctx + CTX_ELEMS;

  unsigned short* featbf = (unsigned short*)d_ws;                 // 16.8 MB
  unsigned short* attbf  = featbf + (size_t)NB * 256 * HW;        // 33.6 MB
  float* rsum_part = (float*)(attbf + (size_t)4096 * HW);         // 256 KB (16 pblocks)
  float* rsum = rsum_part + 16 * 4096;                            // 16 KB
  float* partial = rsum + 4096;                                   // 33.6 MB (8 x 4 MB)

  k_main<<<1536, 256, 0, stream>>>(x, Wa, Wf, ba, bfeat, attbf, featbf, rsum_part);
  k_ctx<<<1024, 256, 0, stream>>>(featbf, attbf, rsum_part, rsum, partial);
  k_final<<<5120, 256, 0, stream>>>(partial, rsum, attbf, ctx, attn);
}

// Round 13
// 147.456 us; speedup vs baseline: 1.0857x; 1.0118x over previous
//
#include <hip/hip_runtime.h>
#include <hip/hip_bf16.h>

#define HW    4096
#define CIN   256
#define NB    8
#define T_FR  8
#define CTX_ELEMS (NB * 256 * 512)      // 1,048,576 = 2^20

typedef __attribute__((ext_vector_type(8))) short short8;
typedef __attribute__((ext_vector_type(4))) float f32x4;

__device__ __forceinline__ unsigned short f2bf(float f) {
  __hip_bfloat16 h = __float2bfloat16(f);
  union { __hip_bfloat16 h; unsigned short u; } v; v.h = h;
  return v.u;
}
__device__ __forceinline__ float bf2f(unsigned short u) {
  union { unsigned int u; float f; } v; v.u = ((unsigned int)u) << 16;
  return v.f;
}

// ---------------------------------------------------------------------------
// k_main: merged att + feat, 256-p tile (64 p per wave, acc[4][4]).
//   blocks [0,1024):    att: (pb = bid&15, s = bid>>4)
//   blocks [1024,1536): feat: (fb=bid-1024: pb = fb&15, g=fb>>4, ftile=g&3, b=g>>2)
// A = x^T per-lane direct global gather (f32->bf16), B = 64xCIN weight slice
// staged bf16 in LDS.  33.8 KB LDS.   (round-9 proven version, verbatim)
// ---------------------------------------------------------------------------
#define LROW 264
__global__ __launch_bounds__(256) void k_main(
    const float* __restrict__ x, const float* __restrict__ Wa,
    const float* __restrict__ Wf, const float* __restrict__ batt,
    const float* __restrict__ bfeat, unsigned short* __restrict__ attbf,
    unsigned short* __restrict__ featbf, float* __restrict__ rsum_part) {
  const int bid = blockIdx.x;
  __shared__ unsigned short Wsh[64 * LROW];    // 33.8 KB
  __shared__ float wsum[4][64];
  const int tid = threadIdx.x, lane = tid & 63, wave = tid >> 6;

  const bool is_att = bid < 1024;
  int pb, s, ftile, b;
  const float* Wsrc;
  if (is_att) {
    pb = bid & 15; s = bid >> 4; ftile = 0; b = 0;
    Wsrc = Wa;
  } else {
    const int fb = bid - 1024;
    pb = fb & 15;
    const int g = fb >> 4;
    ftile = g & 3; b = g >> 2; s = b * T_FR;   // frame 0 of clip b
    Wsrc = Wf + (size_t)(ftile * 64) * CIN;
  }

  // stage 64 rows x 256 cols of Wsrc -> bf16 LDS
  {
    const int row = tid >> 2, seg = tid & 3;
    const float* src = Wsrc + (size_t)row * CIN + seg * 64;
    unsigned short* dst = &Wsh[row * LROW + seg * 64];
#pragma unroll
    for (int i = 0; i < 8; ++i) {
      float4 va = *(const float4*)(src + i * 8);
      float4 vb = *(const float4*)(src + i * 8 + 4);
      short8 w;
      w[0] = (short)f2bf(va.x); w[1] = (short)f2bf(va.y);
      w[2] = (short)f2bf(va.z); w[3] = (short)f2bf(va.w);
      w[4] = (short)f2bf(vb.x); w[5] = (short)f2bf(vb.y);
      w[6] = (short)f2bf(vb.z); w[7] = (short)f2bf(vb.w);
      *(short8*)(dst + i * 8) = w;
    }
  }
  __syncthreads();

  const int r = lane & 15, kg = lane >> 4;
  const int pw = pb * 256 + wave * 64;
  const float* xs = x + (size_t)s * CIN * HW;
  f32x4 acc[4][4] = {};
  for (int ks = 0; ks < 8; ++ks) {
    short8 afr[4];
#pragma unroll
    for (int mi = 0; mi < 4; ++mi) {
      const float* col = xs + (size_t)(ks * 32 + kg * 8) * HW + pw + mi * 16 + r;
#pragma unroll
      for (int j = 0; j < 8; ++j) afr[mi][j] = (short)f2bf(col[(size_t)j * HW]);
    }
    short8 bfr[4];
#pragma unroll
    for (int nj = 0; nj < 4; ++nj)
      bfr[nj] = *(const short8*)&Wsh[(nj * 16 + r) * LROW + ks * 32 + kg * 8];
#pragma unroll
    for (int mi = 0; mi < 4; ++mi)
#pragma unroll
      for (int nj = 0; nj < 4; ++nj)
        acc[mi][nj] = __builtin_amdgcn_mfma_f32_16x16x32_bf16(afr[mi], bfr[nj], acc[mi][nj], 0, 0, 0);
  }

  if (is_att) {
    const int bb = s >> 3, t = s & 7;
    float rowpart[4];
#pragma unroll
    for (int nj = 0; nj < 4; ++nj) {
      const int a = nj * 16 + r;
      const float bias = batt[a];
      float sp = 0.f;
#pragma unroll
      for (int mi = 0; mi < 4; ++mi) {
        float e0 = __expf(acc[mi][nj][0] + bias);
        float e1 = __expf(acc[mi][nj][1] + bias);
        float e2 = __expf(acc[mi][nj][2] + bias);
        float e3 = __expf(acc[mi][nj][3] + bias);
        sp += e0 + e1 + e2 + e3;
        ushort4 u;
        u.x = f2bf(e0); u.y = f2bf(e1); u.z = f2bf(e2); u.w = f2bf(e3);
        *(ushort4*)&attbf[(size_t)(bb * 512 + t * 64 + a) * HW + pw + mi * 16 + kg * 4] = u;
      }
      sp += __shfl_xor(sp, 16);
      sp += __shfl_xor(sp, 32);
      rowpart[nj] = sp;
    }
    if (lane < 16) {
#pragma unroll
      for (int nj = 0; nj < 4; ++nj) wsum[wave][nj * 16 + r] = rowpart[nj];
    }
    __syncthreads();
    if (tid < 64) {
      float tot = wsum[0][tid] + wsum[1][tid] + wsum[2][tid] + wsum[3][tid];
      rsum_part[(size_t)pb * 4096 + bb * 512 + t * 64 + tid] = tot;
    }
  } else {
#pragma unroll
    for (int nj = 0; nj < 4; ++nj) {
      const int f = ftile * 64 + nj * 16 + r;
      const float bias = bfeat[f];
#pragma unroll
      for (int mi = 0; mi < 4; ++mi) {
        ushort4 u;
        u.x = f2bf(acc[mi][nj][0] + bias);
        u.y = f2bf(acc[mi][nj][1] + bias);
        u.z = f2bf(acc[mi][nj][2] + bias);
        u.w = f2bf(acc[mi][nj][3] + bias);
        *(ushort4*)&featbf[(size_t)(b * 256 + f) * HW + pw + mi * 16 + kg * 4] = u;
      }
    }
  }
}

// ---------------------------------------------------------------------------
// k_ctx: split-K(8) partial GEMM (round-9 structure and inner loop verbatim;
// grid back to dim3(8,2,64)) + fused rsum reduction.  ONLY change vs round 9:
// partial stored as bf16 (halves partial write+read traffic; error ~1e-5 on
// ctx after the /rsum division).
//   partial[kc][b][f][a] = sum_{p in kc-chunk} feat[b,f,p]*e[b,a,p]  (bf16)
// Block: 128f x 64a, K = 512.  Grid (8 atile, 2 ftile, 64 = b*8+kc).
// ---------------------------------------------------------------------------
__global__ __launch_bounds__(256) void k_ctx(
    const unsigned short* __restrict__ featbf,
    const unsigned short* __restrict__ attbf,
    const float* __restrict__ rsum_part,
    float* __restrict__ rsum,
    unsigned short* __restrict__ partial) {
  const int a0 = blockIdx.x * 64;
  const int ft = blockIdx.y;
  const int b  = blockIdx.z >> 3;
  const int kc = blockIdx.z & 7;
  const int tid = threadIdx.x, lane = tid & 63, wave = tid >> 6;

  // fused rsum: 16 blocks x 256 threads cover all 4096 rows
  if (blockIdx.x == 0 && blockIdx.y == 0 && blockIdx.z < 16) {
    const int row = blockIdx.z * 256 + tid;
    float s = 0.f;
#pragma unroll
    for (int j = 0; j < 16; ++j) s += rsum_part[(size_t)j * 4096 + row];
    rsum[row] = s;
  }

  __shared__ unsigned short Bsh[64 * LROW];    // 33.8 KB
  const int r = lane & 15, kg = lane >> 4;
  const int fbase = ft * 128 + wave * 32;
  const unsigned short* Arow = featbf + (size_t)(b * 256 + fbase + r) * HW + kc * 512 + kg * 8;
  const unsigned short* Bsrc = attbf + (size_t)(b * 512 + a0 + (tid >> 2)) * HW + kc * 512 + (tid & 3) * 64;
  unsigned short* Bdst = &Bsh[(tid >> 2) * LROW + (tid & 3) * 64];
  f32x4 acc[2][4] = {};
  for (int ch = 0; ch < 2; ++ch) {
    __syncthreads();
#pragma unroll
    for (int i = 0; i < 8; ++i)
      *(short8*)(Bdst + i * 8) = *(const short8*)(Bsrc + ch * 256 + i * 8);
    __syncthreads();
#pragma unroll
    for (int ks = 0; ks < 8; ++ks) {
      short8 afr[2];
      afr[0] = *(const short8*)(Arow + ch * 256 + ks * 32);
      afr[1] = *(const short8*)(Arow + ch * 256 + ks * 32 + (size_t)16 * HW);
      short8 bfr[4];
#pragma unroll
      for (int nj = 0; nj < 4; ++nj)
        bfr[nj] = *(const short8*)&Bsh[(nj * 16 + r) * LROW + ks * 32 + kg * 8];
#pragma unroll
      for (int mi = 0; mi < 2; ++mi)
#pragma unroll
        for (int nj = 0; nj < 4; ++nj)
          acc[mi][nj] = __builtin_amdgcn_mfma_f32_16x16x32_bf16(afr[mi], bfr[nj], acc[mi][nj], 0, 0, 0);
    }
  }
  const size_t base = ((size_t)kc << 20) + (size_t)b * (256 * 512);
#pragma unroll
  for (int mi = 0; mi < 2; ++mi)
#pragma unroll
    for (int nj = 0; nj < 4; ++nj)
#pragma unroll
      for (int reg = 0; reg < 4; ++reg) {
        const int f = fbase + mi * 16 + kg * 4 + reg;
        const int a = a0 + nj * 16 + r;
        partial[base + (size_t)f * 512 + a] = f2bf(acc[mi][nj][reg]);
      }
}

// ---------------------------------------------------------------------------
// k_final: merged epilogue (round-9 structure; partial now bf16).
//   blocks [0,1024):    ctxred: ushort4 loads per kc, f32 accumulate.
//   blocks [1024,5120): attn[row,:] = e_bf16[row,:] / rsum[row]
// ---------------------------------------------------------------------------
__global__ __launch_bounds__(256) void k_final(
    const unsigned short* __restrict__ partial, const float* __restrict__ rsum,
    const unsigned short* __restrict__ attbf,
    float* __restrict__ ctx, float* __restrict__ attn) {
  if (blockIdx.x < 1024) {
    const int i4 = (blockIdx.x * 256 + threadIdx.x) * 4;
    const int a = i4 & 511, b = i4 >> 17;
    float4 s = {0.f, 0.f, 0.f, 0.f};
#pragma unroll
    for (int kc = 0; kc < 8; ++kc) {
      ushort4 p = *(const ushort4*)&partial[((size_t)kc << 20) + i4];
      s.x += bf2f(p.x); s.y += bf2f(p.y); s.z += bf2f(p.z); s.w += bf2f(p.w);
    }
    const float4 rs = *(const float4*)&rsum[b * 512 + a];
    s.x /= rs.x; s.y /= rs.y; s.z /= rs.z; s.w /= rs.w;
    *(float4*)&ctx[i4] = s;
  } else {
    const int row = blockIdx.x - 1024;
    const float inv = 1.0f / rsum[row];
    const unsigned short* src = attbf + (size_t)row * HW;
    float* dst = attn + (size_t)row * HW;
    const int tid = threadIdx.x;
#pragma unroll
    for (int i = 0; i < 2; ++i) {
      short8 v = *(const short8*)(src + tid * 8 + i * 2048);
      float4 o0, o1;
      o0.x = bf2f((unsigned short)v[0]) * inv;
      o0.y = bf2f((unsigned short)v[1]) * inv;
      o0.z = bf2f((unsigned short)v[2]) * inv;
      o0.w = bf2f((unsigned short)v[3]) * inv;
      o1.x = bf2f((unsigned short)v[4]) * inv;
      o1.y = bf2f((unsigned short)v[5]) * inv;
      o1.z = bf2f((unsigned short)v[6]) * inv;
      o1.w = bf2f((unsigned short)v[7]) * inv;
      *(float4*)(dst + tid * 8 + i * 2048) = o0;
      *(float4*)(dst + tid * 8 + i * 2048 + 4) = o1;
    }
  }
}

// ---------------------------------------------------------------------------
extern "C" void kernel_launch(void* const* d_in, const int* in_sizes, int n_in,
                              void* d_out, int out_size, void* d_ws, size_t ws_size,
                              hipStream_t stream) {
  const float* x     = (const float*)d_in[0];
  const float* Wf    = (const float*)d_in[1];
  const float* bfeat = (const float*)d_in[2];
  const float* Wa    = (const float*)d_in[3];
  const float* ba    = (const float*)d_in[4];
  float* ctx  = (float*)d_out;
  float* attn = ctx + CTX_ELEMS;

  unsigned short* featbf = (unsigned short*)d_ws;                 // 16.8 MB
  unsigned short* attbf  = featbf + (size_t)NB * 256 * HW;        // 33.6 MB
  float* rsum_part = (float*)(attbf + (size_t)4096 * HW);         // 256 KB (16 pblocks)
  float* rsum = rsum_part + 16 * 4096;                            // 16 KB
  unsigned short* partial = (unsigned short*)(rsum + 4096);       // 16.8 MB bf16 (8 x 2 MB)

  k_main<<<1536, 256, 0, stream>>>(x, Wa, Wf, ba, bfeat, attbf, featbf, rsum_part);
  k_ctx<<<dim3(8, 2, 64), 256, 0, stream>>>(featbf, attbf, rsum_part, rsum, partial);
  k_final<<<5120, 256, 0, stream>>>(partial, rsum, attbf, ctx, attn);
}

// Round 14
// 143.802 us; speedup vs baseline: 1.1133x; 1.0254x over previous
//
#include <hip/hip_runtime.h>
#include <hip/hip_bf16.h>

#define HW    4096
#define CIN   256
#define NB    8
#define T_FR  8
#define CTX_ELEMS (NB * 256 * 512)      // 1,048,576 = 2^20

typedef __attribute__((ext_vector_type(8))) short short8;
typedef __attribute__((ext_vector_type(4))) float f32x4;

__device__ __forceinline__ unsigned short f2bf(float f) {
  __hip_bfloat16 h = __float2bfloat16(f);
  union { __hip_bfloat16 h; unsigned short u; } v; v.h = h;
  return v.u;
}
__device__ __forceinline__ float bf2f(unsigned short u) {
  union { unsigned int u; float f; } v; v.u = ((unsigned int)u) << 16;
  return v.f;
}

// ---------------------------------------------------------------------------
// k_main: merged att + feat, 256-p tile (64 p per wave, acc[4][4]).
// Round-9 math verbatim; ONLY the bid->work decode changed so that the 4 feat
// blocks of (b,pb) dispatch immediately after their twin att(s=8b,pb) block
// (same 256KB x-slice -> L2/L3 hit instead of HBM refetch, ~33.5 MB saved).
//   per clip b (192 blocks):
//     rem <  80: pb = rem/5, q = rem%5; q==0 -> att(s=8b,pb); q>0 -> feat ftile=q-1
//     rem >= 80: att(s = 8b+1+(rem-80)/16, pb = (rem-80)%16)
// A = x^T per-lane direct global gather (f32->bf16), B = 64xCIN weight slice
// staged bf16 in LDS.  33.8 KB LDS.
// ---------------------------------------------------------------------------
#define LROW 264
__global__ __launch_bounds__(256) void k_main(
    const float* __restrict__ x, const float* __restrict__ Wa,
    const float* __restrict__ Wf, const float* __restrict__ batt,
    const float* __restrict__ bfeat, unsigned short* __restrict__ attbf,
    unsigned short* __restrict__ featbf, float* __restrict__ rsum_part) {
  const int bid = blockIdx.x;
  __shared__ unsigned short Wsh[64 * LROW];    // 33.8 KB
  __shared__ float wsum[4][64];
  const int tid = threadIdx.x, lane = tid & 63, wave = tid >> 6;

  const int bg  = bid / 192;          // clip index
  const int rem = bid - bg * 192;
  bool is_att;
  int pb, s, ftile;
  const int b = bg;
  const float* Wsrc;
  if (rem < 80) {
    pb = rem / 5;
    const int q = rem - pb * 5;
    if (q == 0) { is_att = true;  ftile = 0;     s = 8 * bg; Wsrc = Wa; }
    else        { is_att = false; ftile = q - 1; s = 8 * bg; Wsrc = Wf + (size_t)(ftile * 64) * CIN; }
  } else {
    is_att = true; ftile = 0;
    const int rem2 = rem - 80;
    s  = 8 * bg + 1 + (rem2 >> 4);
    pb = rem2 & 15;
    Wsrc = Wa;
  }

  // stage 64 rows x 256 cols of Wsrc -> bf16 LDS
  {
    const int row = tid >> 2, seg = tid & 3;
    const float* src = Wsrc + (size_t)row * CIN + seg * 64;
    unsigned short* dst = &Wsh[row * LROW + seg * 64];
#pragma unroll
    for (int i = 0; i < 8; ++i) {
      float4 va = *(const float4*)(src + i * 8);
      float4 vb = *(const float4*)(src + i * 8 + 4);
      short8 w;
      w[0] = (short)f2bf(va.x); w[1] = (short)f2bf(va.y);
      w[2] = (short)f2bf(va.z); w[3] = (short)f2bf(va.w);
      w[4] = (short)f2bf(vb.x); w[5] = (short)f2bf(vb.y);
      w[6] = (short)f2bf(vb.z); w[7] = (short)f2bf(vb.w);
      *(short8*)(dst + i * 8) = w;
    }
  }
  __syncthreads();

  const int r = lane & 15, kg = lane >> 4;
  const int pw = pb * 256 + wave * 64;
  const float* xs = x + (size_t)s * CIN * HW;
  f32x4 acc[4][4] = {};
  for (int ks = 0; ks < 8; ++ks) {
    short8 afr[4];
#pragma unroll
    for (int mi = 0; mi < 4; ++mi) {
      const float* col = xs + (size_t)(ks * 32 + kg * 8) * HW + pw + mi * 16 + r;
#pragma unroll
      for (int j = 0; j < 8; ++j) afr[mi][j] = (short)f2bf(col[(size_t)j * HW]);
    }
    short8 bfr[4];
#pragma unroll
    for (int nj = 0; nj < 4; ++nj)
      bfr[nj] = *(const short8*)&Wsh[(nj * 16 + r) * LROW + ks * 32 + kg * 8];
#pragma unroll
    for (int mi = 0; mi < 4; ++mi)
#pragma unroll
      for (int nj = 0; nj < 4; ++nj)
        acc[mi][nj] = __builtin_amdgcn_mfma_f32_16x16x32_bf16(afr[mi], bfr[nj], acc[mi][nj], 0, 0, 0);
  }

  if (is_att) {
    const int bb = s >> 3, t = s & 7;
    float rowpart[4];
#pragma unroll
    for (int nj = 0; nj < 4; ++nj) {
      const int a = nj * 16 + r;
      const float bias = batt[a];
      float sp = 0.f;
#pragma unroll
      for (int mi = 0; mi < 4; ++mi) {
        float e0 = __expf(acc[mi][nj][0] + bias);
        float e1 = __expf(acc[mi][nj][1] + bias);
        float e2 = __expf(acc[mi][nj][2] + bias);
        float e3 = __expf(acc[mi][nj][3] + bias);
        sp += e0 + e1 + e2 + e3;
        ushort4 u;
        u.x = f2bf(e0); u.y = f2bf(e1); u.z = f2bf(e2); u.w = f2bf(e3);
        *(ushort4*)&attbf[(size_t)(bb * 512 + t * 64 + a) * HW + pw + mi * 16 + kg * 4] = u;
      }
      sp += __shfl_xor(sp, 16);
      sp += __shfl_xor(sp, 32);
      rowpart[nj] = sp;
    }
    if (lane < 16) {
#pragma unroll
      for (int nj = 0; nj < 4; ++nj) wsum[wave][nj * 16 + r] = rowpart[nj];
    }
    __syncthreads();
    if (tid < 64) {
      float tot = wsum[0][tid] + wsum[1][tid] + wsum[2][tid] + wsum[3][tid];
      rsum_part[(size_t)pb * 4096 + bb * 512 + t * 64 + tid] = tot;
    }
  } else {
#pragma unroll
    for (int nj = 0; nj < 4; ++nj) {
      const int f = ftile * 64 + nj * 16 + r;
      const float bias = bfeat[f];
#pragma unroll
      for (int mi = 0; mi < 4; ++mi) {
        ushort4 u;
        u.x = f2bf(acc[mi][nj][0] + bias);
        u.y = f2bf(acc[mi][nj][1] + bias);
        u.z = f2bf(acc[mi][nj][2] + bias);
        u.w = f2bf(acc[mi][nj][3] + bias);
        *(ushort4*)&featbf[(size_t)(b * 256 + f) * HW + pw + mi * 16 + kg * 4] = u;
      }
    }
  }
}

// ---------------------------------------------------------------------------
// k_ctx: split-K(8) partial GEMM (round-9 version VERBATIM) + fused rsum.
//   partial[kc][b][f][a] = sum_{p in kc-chunk} feat[b,f,p]*e[b,a,p]  (f32)
// A = featbf direct global (K-contig), B = attbf staged in LDS.
// Block: 128f x 64a, K = 512.  Grid (8 atile, 2 ftile, 64 = b*8+kc).
// ---------------------------------------------------------------------------
__global__ __launch_bounds__(256) void k_ctx(
    const unsigned short* __restrict__ featbf,
    const unsigned short* __restrict__ attbf,
    const float* __restrict__ rsum_part,
    float* __restrict__ rsum,
    float* __restrict__ partial) {
  const int a0 = blockIdx.x * 64;
  const int ft = blockIdx.y;
  const int b  = blockIdx.z >> 3;
  const int kc = blockIdx.z & 7;
  const int tid = threadIdx.x, lane = tid & 63, wave = tid >> 6;

  // fused rsum: 16 blocks x 256 threads cover all 4096 rows
  if (blockIdx.x == 0 && blockIdx.y == 0 && blockIdx.z < 16) {
    const int row = blockIdx.z * 256 + tid;
    float s = 0.f;
#pragma unroll
    for (int j = 0; j < 16; ++j) s += rsum_part[(size_t)j * 4096 + row];
    rsum[row] = s;
  }

  __shared__ unsigned short Bsh[64 * LROW];    // 33.8 KB
  const int r = lane & 15, kg = lane >> 4;
  const int fbase = ft * 128 + wave * 32;
  const unsigned short* Arow = featbf + (size_t)(b * 256 + fbase + r) * HW + kc * 512 + kg * 8;
  const unsigned short* Bsrc = attbf + (size_t)(b * 512 + a0 + (tid >> 2)) * HW + kc * 512 + (tid & 3) * 64;
  unsigned short* Bdst = &Bsh[(tid >> 2) * LROW + (tid & 3) * 64];
  f32x4 acc[2][4] = {};
  for (int ch = 0; ch < 2; ++ch) {
    __syncthreads();
#pragma unroll
    for (int i = 0; i < 8; ++i)
      *(short8*)(Bdst + i * 8) = *(const short8*)(Bsrc + ch * 256 + i * 8);
    __syncthreads();
#pragma unroll
    for (int ks = 0; ks < 8; ++ks) {
      short8 afr[2];
      afr[0] = *(const short8*)(Arow + ch * 256 + ks * 32);
      afr[1] = *(const short8*)(Arow + ch * 256 + ks * 32 + (size_t)16 * HW);
      short8 bfr[4];
#pragma unroll
      for (int nj = 0; nj < 4; ++nj)
        bfr[nj] = *(const short8*)&Bsh[(nj * 16 + r) * LROW + ks * 32 + kg * 8];
#pragma unroll
      for (int mi = 0; mi < 2; ++mi)
#pragma unroll
        for (int nj = 0; nj < 4; ++nj)
          acc[mi][nj] = __builtin_amdgcn_mfma_f32_16x16x32_bf16(afr[mi], bfr[nj], acc[mi][nj], 0, 0, 0);
    }
  }
  const size_t base = ((size_t)kc << 20) + (size_t)b * (256 * 512);
#pragma unroll
  for (int mi = 0; mi < 2; ++mi)
#pragma unroll
    for (int nj = 0; nj < 4; ++nj)
#pragma unroll
      for (int reg = 0; reg < 4; ++reg) {
        const int f = fbase + mi * 16 + kg * 4 + reg;
        const int a = a0 + nj * 16 + r;
        partial[base + (size_t)f * 512 + a] = acc[mi][nj][reg];
      }
}

// ---------------------------------------------------------------------------
// k_final: merged epilogue (round-9 version VERBATIM).
//   blocks [0,1024):    ctxred, float4-vectorized.
//   blocks [1024,5120): attn[row,:] = e_bf16[row,:] / rsum[row]
// ---------------------------------------------------------------------------
__global__ __launch_bounds__(256) void k_final(
    const float* __restrict__ partial, const float* __restrict__ rsum,
    const unsigned short* __restrict__ attbf,
    float* __restrict__ ctx, float* __restrict__ attn) {
  if (blockIdx.x < 1024) {
    const int i4 = (blockIdx.x * 256 + threadIdx.x) * 4;
    const int a = i4 & 511, b = i4 >> 17;
    float4 s = *(const float4*)&partial[i4];
#pragma unroll
    for (int kc = 1; kc < 8; ++kc) {
      float4 p = *(const float4*)&partial[((size_t)kc << 20) + i4];
      s.x += p.x; s.y += p.y; s.z += p.z; s.w += p.w;
    }
    const float4 rs = *(const float4*)&rsum[b * 512 + a];
    s.x /= rs.x; s.y /= rs.y; s.z /= rs.z; s.w /= rs.w;
    *(float4*)&ctx[i4] = s;
  } else {
    const int row = blockIdx.x - 1024;
    const float inv = 1.0f / rsum[row];
    const unsigned short* src = attbf + (size_t)row * HW;
    float* dst = attn + (size_t)row * HW;
    const int tid = threadIdx.x;
#pragma unroll
    for (int i = 0; i < 2; ++i) {
      short8 v = *(const short8*)(src + tid * 8 + i * 2048);
      float4 o0, o1;
      o0.x = bf2f((unsigned short)v[0]) * inv;
      o0.y = bf2f((unsigned short)v[1]) * inv;
      o0.z = bf2f((unsigned short)v[2]) * inv;
      o0.w = bf2f((unsigned short)v[3]) * inv;
      o1.x = bf2f((unsigned short)v[4]) * inv;
      o1.y = bf2f((unsigned short)v[5]) * inv;
      o1.z = bf2f((unsigned short)v[6]) * inv;
      o1.w = bf2f((unsigned short)v[7]) * inv;
      *(float4*)(dst + tid * 8 + i * 2048) = o0;
      *(float4*)(dst + tid * 8 + i * 2048 + 4) = o1;
    }
  }
}

// ---------------------------------------------------------------------------
extern "C" void kernel_launch(void* const* d_in, const int* in_sizes, int n_in,
                              void* d_out, int out_size, void* d_ws, size_t ws_size,
                              hipStream_t stream) {
  const float* x     = (const float*)d_in[0];
  const float* Wf    = (const float*)d_in[1];
  const float* bfeat = (const float*)d_in[2];
  const float* Wa    = (const float*)d_in[3];
  const float* ba    = (const float*)d_in[4];
  float* ctx  = (float*)d_out;
  float* attn = ctx + CTX_ELEMS;

  unsigned short* featbf = (unsigned short*)d_ws;                 // 16.8 MB
  unsigned short* attbf  = featbf + (size_t)NB * 256 * HW;        // 33.6 MB
  float* rsum_part = (float*)(attbf + (size_t)4096 * HW);         // 256 KB (16 pblocks)
  float* rsum = rsum_part + 16 * 4096;                            // 16 KB
  float* partial = rsum + 4096;                                   // 33.6 MB (8 x 4 MB)

  k_main<<<1536, 256, 0, stream>>>(x, Wa, Wf, ba, bfeat, attbf, featbf, rsum_part);
  k_ctx<<<dim3(8, 2, 64), 256, 0, stream>>>(featbf, attbf, rsum_part, rsum, partial);
  k_final<<<5120, 256, 0, stream>>>(partial, rsum, attbf, ctx, attn);
}

// Round 15
// 141.734 us; speedup vs baseline: 1.1296x; 1.0146x over previous
//
#include <hip/hip_runtime.h>
#include <hip/hip_bf16.h>

#define HW    4096
#define CIN   256
#define NB    8
#define T_FR  8
#define CTX_ELEMS (NB * 256 * 512)      // 1,048,576 = 2^20

typedef __attribute__((ext_vector_type(8))) short short8;
typedef __attribute__((ext_vector_type(4))) float f32x4;

__device__ __forceinline__ unsigned short f2bf(float f) {
  __hip_bfloat16 h = __float2bfloat16(f);
  union { __hip_bfloat16 h; unsigned short u; } v; v.h = h;
  return v.u;
}
__device__ __forceinline__ float bf2f(unsigned short u) {
  union { unsigned int u; float f; } v; v.u = ((unsigned int)u) << 16;
  return v.f;
}

// ---------------------------------------------------------------------------
// k_main: merged att + feat, 256-p tile (64 p per wave, acc[4][4]).
//   blocks [0,1024):    att: (pb = bid&15, s = bid>>4)
//   blocks [1024,1536): feat: (fb=bid-1024: pb = fb&15, g=fb>>4, ftile=g&3, b=g>>2)
// A = x^T per-lane direct global gather (f32->bf16), B = 64xCIN weight slice
// staged bf16 in LDS.  33.8 KB LDS.   (round-9 measured optimum, verbatim)
// ---------------------------------------------------------------------------
#define LROW 264
__global__ __launch_bounds__(256) void k_main(
    const float* __restrict__ x, const float* __restrict__ Wa,
    const float* __restrict__ Wf, const float* __restrict__ batt,
    const float* __restrict__ bfeat, unsigned short* __restrict__ attbf,
    unsigned short* __restrict__ featbf, float* __restrict__ rsum_part) {
  const int bid = blockIdx.x;
  __shared__ unsigned short Wsh[64 * LROW];    // 33.8 KB
  __shared__ float wsum[4][64];
  const int tid = threadIdx.x, lane = tid & 63, wave = tid >> 6;

  const bool is_att = bid < 1024;
  int pb, s, ftile, b;
  const float* Wsrc;
  if (is_att) {
    pb = bid & 15; s = bid >> 4; ftile = 0; b = 0;
    Wsrc = Wa;
  } else {
    const int fb = bid - 1024;
    pb = fb & 15;
    const int g = fb >> 4;
    ftile = g & 3; b = g >> 2; s = b * T_FR;   // frame 0 of clip b
    Wsrc = Wf + (size_t)(ftile * 64) * CIN;
  }

  // stage 64 rows x 256 cols of Wsrc -> bf16 LDS
  {
    const int row = tid >> 2, seg = tid & 3;
    const float* src = Wsrc + (size_t)row * CIN + seg * 64;
    unsigned short* dst = &Wsh[row * LROW + seg * 64];
#pragma unroll
    for (int i = 0; i < 8; ++i) {
      float4 va = *(const float4*)(src + i * 8);
      float4 vb = *(const float4*)(src + i * 8 + 4);
      short8 w;
      w[0] = (short)f2bf(va.x); w[1] = (short)f2bf(va.y);
      w[2] = (short)f2bf(va.z); w[3] = (short)f2bf(va.w);
      w[4] = (short)f2bf(vb.x); w[5] = (short)f2bf(vb.y);
      w[6] = (short)f2bf(vb.z); w[7] = (short)f2bf(vb.w);
      *(short8*)(dst + i * 8) = w;
    }
  }
  __syncthreads();

  const int r = lane & 15, kg = lane >> 4;
  const int pw = pb * 256 + wave * 64;
  const float* xs = x + (size_t)s * CIN * HW;
  f32x4 acc[4][4] = {};
  for (int ks = 0; ks < 8; ++ks) {
    short8 afr[4];
#pragma unroll
    for (int mi = 0; mi < 4; ++mi) {
      const float* col = xs + (size_t)(ks * 32 + kg * 8) * HW + pw + mi * 16 + r;
#pragma unroll
      for (int j = 0; j < 8; ++j) afr[mi][j] = (short)f2bf(col[(size_t)j * HW]);
    }
    short8 bfr[4];
#pragma unroll
    for (int nj = 0; nj < 4; ++nj)
      bfr[nj] = *(const short8*)&Wsh[(nj * 16 + r) * LROW + ks * 32 + kg * 8];
#pragma unroll
    for (int mi = 0; mi < 4; ++mi)
#pragma unroll
      for (int nj = 0; nj < 4; ++nj)
        acc[mi][nj] = __builtin_amdgcn_mfma_f32_16x16x32_bf16(afr[mi], bfr[nj], acc[mi][nj], 0, 0, 0);
  }

  if (is_att) {
    const int bb = s >> 3, t = s & 7;
    float rowpart[4];
#pragma unroll
    for (int nj = 0; nj < 4; ++nj) {
      const int a = nj * 16 + r;
      const float bias = batt[a];
      float sp = 0.f;
#pragma unroll
      for (int mi = 0; mi < 4; ++mi) {
        float e0 = __expf(acc[mi][nj][0] + bias);
        float e1 = __expf(acc[mi][nj][1] + bias);
        float e2 = __expf(acc[mi][nj][2] + bias);
        float e3 = __expf(acc[mi][nj][3] + bias);
        sp += e0 + e1 + e2 + e3;
        ushort4 u;
        u.x = f2bf(e0); u.y = f2bf(e1); u.z = f2bf(e2); u.w = f2bf(e3);
        *(ushort4*)&attbf[(size_t)(bb * 512 + t * 64 + a) * HW + pw + mi * 16 + kg * 4] = u;
      }
      sp += __shfl_xor(sp, 16);
      sp += __shfl_xor(sp, 32);
      rowpart[nj] = sp;
    }
    if (lane < 16) {
#pragma unroll
      for (int nj = 0; nj < 4; ++nj) wsum[wave][nj * 16 + r] = rowpart[nj];
    }
    __syncthreads();
    if (tid < 64) {
      float tot = wsum[0][tid] + wsum[1][tid] + wsum[2][tid] + wsum[3][tid];
      rsum_part[(size_t)pb * 4096 + bb * 512 + t * 64 + tid] = tot;
    }
  } else {
#pragma unroll
    for (int nj = 0; nj < 4; ++nj) {
      const int f = ftile * 64 + nj * 16 + r;
      const float bias = bfeat[f];
#pragma unroll
      for (int mi = 0; mi < 4; ++mi) {
        ushort4 u;
        u.x = f2bf(acc[mi][nj][0] + bias);
        u.y = f2bf(acc[mi][nj][1] + bias);
        u.z = f2bf(acc[mi][nj][2] + bias);
        u.w = f2bf(acc[mi][nj][3] + bias);
        *(ushort4*)&featbf[(size_t)(b * 256 + f) * HW + pw + mi * 16 + kg * 4] = u;
      }
    }
  }
}

// ---------------------------------------------------------------------------
// k_ctx: split-K(8) partial GEMM + fused rsum reduction (round-9 verbatim).
//   partial[kc][b][f][a] = sum_{p in kc-chunk} feat[b,f,p]*e[b,a,p]  (f32)
// A = featbf direct global (K-contig), B = attbf staged in LDS.
// Block: 128f x 64a, K = 512.  Grid (8 atile, 2 ftile, 64 = b*8+kc).
// ---------------------------------------------------------------------------
__global__ __launch_bounds__(256) void k_ctx(
    const unsigned short* __restrict__ featbf,
    const unsigned short* __restrict__ attbf,
    const float* __restrict__ rsum_part,
    float* __restrict__ rsum,
    float* __restrict__ partial) {
  const int a0 = blockIdx.x * 64;
  const int ft = blockIdx.y;
  const int b  = blockIdx.z >> 3;
  const int kc = blockIdx.z & 7;
  const int tid = threadIdx.x, lane = tid & 63, wave = tid >> 6;

  // fused rsum: 16 blocks x 256 threads cover all 4096 rows
  if (blockIdx.x == 0 && blockIdx.y == 0 && blockIdx.z < 16) {
    const int row = blockIdx.z * 256 + tid;
    float s = 0.f;
#pragma unroll
    for (int j = 0; j < 16; ++j) s += rsum_part[(size_t)j * 4096 + row];
    rsum[row] = s;
  }

  __shared__ unsigned short Bsh[64 * LROW];    // 33.8 KB
  const int r = lane & 15, kg = lane >> 4;
  const int fbase = ft * 128 + wave * 32;
  const unsigned short* Arow = featbf + (size_t)(b * 256 + fbase + r) * HW + kc * 512 + kg * 8;
  const unsigned short* Bsrc = attbf + (size_t)(b * 512 + a0 + (tid >> 2)) * HW + kc * 512 + (tid & 3) * 64;
  unsigned short* Bdst = &Bsh[(tid >> 2) * LROW + (tid & 3) * 64];
  f32x4 acc[2][4] = {};
  for (int ch = 0; ch < 2; ++ch) {
    __syncthreads();
#pragma unroll
    for (int i = 0; i < 8; ++i)
      *(short8*)(Bdst + i * 8) = *(const short8*)(Bsrc + ch * 256 + i * 8);
    __syncthreads();
#pragma unroll
    for (int ks = 0; ks < 8; ++ks) {
      short8 afr[2];
      afr[0] = *(const short8*)(Arow + ch * 256 + ks * 32);
      afr[1] = *(const short8*)(Arow + ch * 256 + ks * 32 + (size_t)16 * HW);
      short8 bfr[4];
#pragma unroll
      for (int nj = 0; nj < 4; ++nj)
        bfr[nj] = *(const short8*)&Bsh[(nj * 16 + r) * LROW + ks * 32 + kg * 8];
#pragma unroll
      for (int mi = 0; mi < 2; ++mi)
#pragma unroll
        for (int nj = 0; nj < 4; ++nj)
          acc[mi][nj] = __builtin_amdgcn_mfma_f32_16x16x32_bf16(afr[mi], bfr[nj], acc[mi][nj], 0, 0, 0);
    }
  }
  const size_t base = ((size_t)kc << 20) + (size_t)b * (256 * 512);
#pragma unroll
  for (int mi = 0; mi < 2; ++mi)
#pragma unroll
    for (int nj = 0; nj < 4; ++nj)
#pragma unroll
      for (int reg = 0; reg < 4; ++reg) {
        const int f = fbase + mi * 16 + kg * 4 + reg;
        const int a = a0 + nj * 16 + r;
        partial[base + (size_t)f * 512 + a] = acc[mi][nj][reg];
      }
}

// ---------------------------------------------------------------------------
// k_final: merged epilogue (round-9 verbatim).
//   blocks [0,1024):    ctxred, float4-vectorized.
//   blocks [1024,5120): attn[row,:] = e_bf16[row,:] / rsum[row]
// ---------------------------------------------------------------------------
__global__ __launch_bounds__(256) void k_final(
    const float* __restrict__ partial, const float* __restrict__ rsum,
    const unsigned short* __restrict__ attbf,
    float* __restrict__ ctx, float* __restrict__ attn) {
  if (blockIdx.x < 1024) {
    const int i4 = (blockIdx.x * 256 + threadIdx.x) * 4;
    const int a = i4 & 511, b = i4 >> 17;
    float4 s = *(const float4*)&partial[i4];
#pragma unroll
    for (int kc = 1; kc < 8; ++kc) {
      float4 p = *(const float4*)&partial[((size_t)kc << 20) + i4];
      s.x += p.x; s.y += p.y; s.z += p.z; s.w += p.w;
    }
    const float4 rs = *(const float4*)&rsum[b * 512 + a];
    s.x /= rs.x; s.y /= rs.y; s.z /= rs.z; s.w /= rs.w;
    *(float4*)&ctx[i4] = s;
  } else {
    const int row = blockIdx.x - 1024;
    const float inv = 1.0f / rsum[row];
    const unsigned short* src = attbf + (size_t)row * HW;
    float* dst = attn + (size_t)row * HW;
    const int tid = threadIdx.x;
#pragma unroll
    for (int i = 0; i < 2; ++i) {
      short8 v = *(const short8*)(src + tid * 8 + i * 2048);
      float4 o0, o1;
      o0.x = bf2f((unsigned short)v[0]) * inv;
      o0.y = bf2f((unsigned short)v[1]) * inv;
      o0.z = bf2f((unsigned short)v[2]) * inv;
      o0.w = bf2f((unsigned short)v[3]) * inv;
      o1.x = bf2f((unsigned short)v[4]) * inv;
      o1.y = bf2f((unsigned short)v[5]) * inv;
      o1.z = bf2f((unsigned short)v[6]) * inv;
      o1.w = bf2f((unsigned short)v[7]) * inv;
      *(float4*)(dst + tid * 8 + i * 2048) = o0;
      *(float4*)(dst + tid * 8 + i * 2048 + 4) = o1;
    }
  }
}

// ---------------------------------------------------------------------------
extern "C" void kernel_launch(void* const* d_in, const int* in_sizes, int n_in,
                              void* d_out, int out_size, void* d_ws, size_t ws_size,
                              hipStream_t stream) {
  const float* x     = (const float*)d_in[0];
  const float* Wf    = (const float*)d_in[1];
  const float* bfeat = (const float*)d_in[2];
  const float* Wa    = (const float*)d_in[3];
  const float* ba    = (const float*)d_in[4];
  float* ctx  = (float*)d_out;
  float* attn = ctx + CTX_ELEMS;

  unsigned short* featbf = (unsigned short*)d_ws;                 // 16.8 MB
  unsigned short* attbf  = featbf + (size_t)NB * 256 * HW;        // 33.6 MB
  float* rsum_part = (float*)(attbf + (size_t)4096 * HW);         // 256 KB (16 pblocks)
  float* rsum = rsum_part + 16 * 4096;                            // 16 KB
  float* partial = rsum + 4096;                                   // 33.6 MB (8 x 4 MB)

  k_main<<<1536, 256, 0, stream>>>(x, Wa, Wf, ba, bfeat, attbf, featbf, rsum_part);
  k_ctx<<<dim3(8, 2, 64), 256, 0, stream>>>(featbf, attbf, rsum_part, rsum, partial);
  k_final<<<5120, 256, 0, stream>>>(partial, rsum, attbf, ctx, attn);
}